// Round 3
// baseline (1031.557 us; speedup 1.0000x reference)
//
#include <hip/hip_runtime.h>
#include <hip/hip_bf16.h>
#include <cmath>

// ---------------------------------------------------------------------------
// GCN: out = tanh(relu(relu(relu(relu(P(P(P(P(xW1+..)..) .. ))Wf1+bf1)Wf2+bf2
// P = D^-1/2 (A+I) D^-1/2 via CSR (dst-sorted) gather-sum, no float atomics.
// Associativity: aggregate at the *narrower* width of each layer.
// edge_index arrives as int32 (harness converts int64 inputs).
// R2: register-tiled GEMM (RTx4 outputs/thread), float4 aggregation.
// ---------------------------------------------------------------------------

__global__ void zero_kernel(int* p, int n) {
    int i = blockIdx.x * 256 + threadIdx.x;
    if (i < n) p[i] = 0;
}

__global__ void deg_kernel(const int* __restrict__ dst, int* __restrict__ cnt, int E) {
    int e = blockIdx.x * 256 + threadIdx.x;
    if (e < E) atomicAdd(&cnt[dst[e]], 1);
}

__global__ void dinv_kernel(const int* __restrict__ cnt, float* __restrict__ dinv, int N) {
    int i = blockIdx.x * 256 + threadIdx.x;
    if (i < N) dinv[i] = rsqrtf((float)cnt[i] + 1.0f);
}

// --- 3-kernel exclusive scan over per-node counts (N <= 512*256) -----------
__global__ void scan1_kernel(const int* __restrict__ cnt, int* __restrict__ row_ptr,
                             int* __restrict__ blk, int N) {
    __shared__ int s[256];
    int t = threadIdx.x;
    int idx = blockIdx.x * 256 + t;
    int v = (idx < N) ? cnt[idx] : 0;
    s[t] = v; __syncthreads();
    for (int off = 1; off < 256; off <<= 1) {
        int x = (t >= off) ? s[t - off] : 0;
        __syncthreads();
        s[t] += x;
        __syncthreads();
    }
    if (idx < N) row_ptr[idx] = s[t] - v;
    if (t == 255) blk[blockIdx.x] = s[255];
}

__global__ void scan2_kernel(int* __restrict__ blk, int NB) {
    __shared__ int s[512];
    int t = threadIdx.x;
    int v = (t < NB) ? blk[t] : 0;
    s[t] = v; __syncthreads();
    for (int off = 1; off < 512; off <<= 1) {
        int x = (t >= off) ? s[t - off] : 0;
        __syncthreads();
        s[t] += x;
        __syncthreads();
    }
    if (t < NB) blk[t] = s[t] - v;
}

__global__ void scan3_kernel(int* __restrict__ row_ptr, const int* __restrict__ blk,
                             int* __restrict__ cursor, int N, int E) {
    int idx = blockIdx.x * 256 + threadIdx.x;
    if (idx < N) {
        int v = row_ptr[idx] + blk[blockIdx.x];
        row_ptr[idx] = v;
        cursor[idx] = v;
    }
    if (idx == 0) row_ptr[N] = E;
}

__global__ void fill_kernel(const int* __restrict__ src, const int* __restrict__ dst,
                            const float* __restrict__ dinv, int* __restrict__ cursor,
                            int* __restrict__ csr_src, float* __restrict__ csr_w, int E) {
    int e = blockIdx.x * 256 + threadIdx.x;
    if (e >= E) return;
    int s = src[e];
    int d = dst[e];
    float w = dinv[s] * dinv[d];
    int pos = atomicAdd(&cursor[d], 1);
    csr_src[pos] = s;
    csr_w[pos] = w;
}

// --- aggregation: out[i,:] = sum_e w_e * z[src_e,:] + dinv[i]^2 * z[i,:] ----
// one wave per node; F/4 lanes per edge-slot read the row as float4;
// S = 256/F slots per wave; butterfly float4 shuffle over slot bits.
template<int F, bool L1MODE>
__global__ __launch_bounds__(256) void agg_kernel(
        const float* __restrict__ z, const int* __restrict__ row_ptr,
        const int* __restrict__ csr_src, const float* __restrict__ csr_w,
        const float* __restrict__ dinv, const float* __restrict__ bias,
        float* __restrict__ out, int N) {
    constexpr int G = F / 4;       // lanes per row
    constexpr int S = 64 / G;      // edge slots per wave
    const int t = threadIdx.x;
    const int wave = t >> 6;
    const int lane = t & 63;
    const int slot = lane / G;
    const int f4 = lane % G;       // float4 index within row
    const int i = blockIdx.x * 4 + wave;
    if (i >= N) return;            // wave-uniform exit
    const int start = row_ptr[i];
    const int end = row_ptr[i + 1];
    float4 acc = {0.f, 0.f, 0.f, 0.f};
    for (int e = start + slot; e < end; e += S) {
        int s = csr_src[e];
        float w = csr_w[e];
        float4 zv = *(const float4*)&z[(size_t)s * F + f4 * 4];
        acc.x += w * zv.x; acc.y += w * zv.y; acc.z += w * zv.z; acc.w += w * zv.w;
    }
#pragma unroll
    for (int off = G; off < 64; off <<= 1) {
        acc.x += __shfl_xor(acc.x, off);
        acc.y += __shfl_xor(acc.y, off);
        acc.z += __shfl_xor(acc.z, off);
        acc.w += __shfl_xor(acc.w, off);
    }
    if (slot == 0) {
        float di = dinv[i];
        float d2 = di * di;
        float4 zs = *(const float4*)&z[(size_t)i * F + f4 * 4];
        float4 r;
        r.x = acc.x + d2 * zs.x; r.y = acc.y + d2 * zs.y;
        r.z = acc.z + d2 * zs.z; r.w = acc.w + d2 * zs.w;
        if (L1MODE) {
            float4 bv = *(const float4*)&bias[f4 * 4];
            r.x = fmaxf(r.x + bv.x, 0.f); r.y = fmaxf(r.y + bv.y, 0.f);
            r.z = fmaxf(r.z + bv.z, 0.f); r.w = fmaxf(r.w + bv.w, 0.f);
        }
        *(float4*)&out[(size_t)i * F + f4 * 4] = r;
    }
}

// --- register-tiled GEMM: 64-row x M-col tile per 256-thread block ----------
// thread: RT rows x 4 cols. A tile in LDS (stride K+4), W tile flat in LDS.
// inner loop k-step 4: RT+4 ds_read_b128 per 16*RT FMAs.
template<int K, int M, int RT, bool BIAS_RELU>
__global__ __launch_bounds__(256) void gemm_kernel(
        const float* __restrict__ A, const float* __restrict__ W,
        const float* __restrict__ bias, float* __restrict__ out, int N) {
    constexpr int CG = M / 4;            // column groups
    constexpr int TM = (256 / CG) * RT;  // rows per block (=64 for all layers)
    constexpr int KP = K + 4;
    static_assert(TM == 64, "tile rows");
    __shared__ float As[TM * KP];
    __shared__ float Ws[K * M];
    __shared__ float bs[M > 0 ? M : 1];
    const int t = threadIdx.x;
    const int base = blockIdx.x * TM;
    const int rows_valid = min(TM, N - base);
    constexpr int KD4 = K / 4;
    for (int idx = t; idx < TM * KD4; idx += 256) {
        int row = idx / KD4, kc = idx % KD4;
        if (row < rows_valid)
            *(float4*)&As[row * KP + kc * 4] = *(const float4*)&A[(size_t)(base + row) * K + kc * 4];
    }
    for (int idx = t; idx < K * M / 4; idx += 256)
        *(float4*)&Ws[idx * 4] = *(const float4*)&W[idx * 4];
    if (BIAS_RELU && t < M) bs[t] = bias[t];
    __syncthreads();

    const int tc = t % CG;
    const int r0 = (t / CG) * RT;
    const int c0 = tc * 4;
    float4 acc[RT];
#pragma unroll
    for (int r = 0; r < RT; r++) acc[r] = {0.f, 0.f, 0.f, 0.f};

#pragma unroll
    for (int k = 0; k < K; k += 4) {
        float4 w0 = *(const float4*)&Ws[(k + 0) * M + c0];
        float4 w1 = *(const float4*)&Ws[(k + 1) * M + c0];
        float4 w2 = *(const float4*)&Ws[(k + 2) * M + c0];
        float4 w3 = *(const float4*)&Ws[(k + 3) * M + c0];
#pragma unroll
        for (int r = 0; r < RT; r++) {
            float4 av = *(const float4*)&As[(r0 + r) * KP + k];
            acc[r].x += av.x * w0.x + av.y * w1.x + av.z * w2.x + av.w * w3.x;
            acc[r].y += av.x * w0.y + av.y * w1.y + av.z * w2.y + av.w * w3.y;
            acc[r].z += av.x * w0.z + av.y * w1.z + av.z * w2.z + av.w * w3.z;
            acc[r].w += av.x * w0.w + av.y * w1.w + av.z * w2.w + av.w * w3.w;
        }
    }
#pragma unroll
    for (int r = 0; r < RT; r++) {
        int row = base + r0 + r;
        if (row < N) {
            float4 v = acc[r];
            if (BIAS_RELU) {
                float4 bv = *(const float4*)&bs[c0];
                v.x = fmaxf(v.x + bv.x, 0.f); v.y = fmaxf(v.y + bv.y, 0.f);
                v.z = fmaxf(v.z + bv.z, 0.f); v.w = fmaxf(v.w + bv.w, 0.f);
            }
            *(float4*)&out[(size_t)row * M + c0] = v;
        }
    }
}

// --- final FC: K=32, M=10, tanh --------------------------------------------
__global__ __launch_bounds__(256) void fc2_tanh_kernel(
        const float* __restrict__ A, const float* __restrict__ W,
        const float* __restrict__ bias, float* __restrict__ out, int N) {
    __shared__ float wt[10][36];
    __shared__ float bs[10];
    int t = threadIdx.x;
    for (int idx = t; idx < 320; idx += 256) { int k = idx / 10, m = idx % 10; wt[m][k] = W[idx]; }
    if (t < 10) bs[t] = bias[t];
    __syncthreads();
    int row = blockIdx.x * 256 + t;
    if (row >= N) return;
    float a[32];
    const float4* ap = (const float4*)(A + (size_t)row * 32);
#pragma unroll
    for (int j = 0; j < 8; j++) {
        float4 v = ap[j];
        a[4 * j] = v.x; a[4 * j + 1] = v.y; a[4 * j + 2] = v.z; a[4 * j + 3] = v.w;
    }
#pragma unroll
    for (int m = 0; m < 10; m++) {
        float acc = bs[m];
#pragma unroll
        for (int k = 0; k < 32; k++) acc += a[k] * wt[m][k];
        out[(size_t)row * 10 + m] = tanhf(acc);
    }
}

extern "C" void kernel_launch(void* const* d_in, const int* in_sizes, int n_in,
                              void* d_out, int out_size, void* d_ws, size_t ws_size,
                              hipStream_t stream) {
    const float* x   = (const float*)d_in[0];
    const int*   ei  = (const int*)d_in[1];     // int32 on device
    const float* W1  = (const float*)d_in[2];
    const float* b1  = (const float*)d_in[3];
    const float* W2  = (const float*)d_in[4];
    const float* b2  = (const float*)d_in[5];
    const float* W3  = (const float*)d_in[6];
    const float* b3  = (const float*)d_in[7];
    const float* W4  = (const float*)d_in[8];
    const float* b4  = (const float*)d_in[9];
    const float* Wf1 = (const float*)d_in[10];
    const float* bf1 = (const float*)d_in[11];
    const float* Wf2 = (const float*)d_in[12];
    const float* bf2 = (const float*)d_in[13];

    const int N = in_sizes[0] / 128;   // 100000
    const int E = in_sizes[1] / 2;     // 1600000
    const int* e_src = ei;
    const int* e_dst = ei + E;

    char* p = (char*)d_ws;
    auto carve = [&](size_t bytes) -> void* {
        void* r = (void*)p;
        p += (bytes + 255) & ~(size_t)255;
        return r;
    };
    int*   cnt     = (int*)carve((size_t)N * 4);          // reused as cursor
    float* dinv    = (float*)carve((size_t)N * 4);
    int*   row_ptr = (int*)carve((size_t)(N + 1) * 4);
    int*   blk     = (int*)carve(512 * 4);
    int*   csr_src = (int*)carve((size_t)E * 4);
    float* csr_w   = (float*)carve((size_t)E * 4);
    float* bufA    = (float*)carve((size_t)N * 64 * 4);
    float* bufB    = (float*)carve((size_t)N * 128 * 4);

    const int NB  = (N + 255) / 256;   // 391
    const int EB  = (E + 255) / 256;
    const int AGB = (N + 3) / 4;
    const int GB  = (N + 63) / 64;     // 1563 gemm blocks

    // --- graph preprocessing: degree, dinv, CSR ---
    zero_kernel<<<NB, 256, 0, stream>>>(cnt, N);
    deg_kernel<<<EB, 256, 0, stream>>>(e_dst, cnt, E);
    dinv_kernel<<<NB, 256, 0, stream>>>(cnt, dinv, N);
    scan1_kernel<<<NB, 256, 0, stream>>>(cnt, row_ptr, blk, N);
    scan2_kernel<<<1, 512, 0, stream>>>(blk, NB);
    scan3_kernel<<<NB, 256, 0, stream>>>(row_ptr, blk, cnt, N, E);
    fill_kernel<<<EB, 256, 0, stream>>>(e_src, e_dst, dinv, cnt, csr_src, csr_w, E);

    // --- L1 (128->16): GEMM first (narrow side), then aggregate+bias+relu ---
    gemm_kernel<128, 16, 1, false><<<GB, 256, 0, stream>>>(x, W1, nullptr, bufA, N);
    agg_kernel<16, true><<<AGB, 256, 0, stream>>>(bufA, row_ptr, csr_src, csr_w, dinv, b1, bufB, N);

    // --- L2 (16->32): aggregate first, then GEMM+bias+relu ---
    agg_kernel<16, false><<<AGB, 256, 0, stream>>>(bufB, row_ptr, csr_src, csr_w, dinv, nullptr, bufA, N);
    gemm_kernel<16, 32, 2, true><<<GB, 256, 0, stream>>>(bufA, W2, b2, bufB, N);

    // --- L3 (32->64) ---
    agg_kernel<32, false><<<AGB, 256, 0, stream>>>(bufB, row_ptr, csr_src, csr_w, dinv, nullptr, bufA, N);
    gemm_kernel<32, 64, 4, true><<<GB, 256, 0, stream>>>(bufA, W3, b3, bufB, N);

    // --- L4 (64->128) ---
    agg_kernel<64, false><<<AGB, 256, 0, stream>>>(bufB, row_ptr, csr_src, csr_w, dinv, nullptr, bufA, N);
    gemm_kernel<64, 128, 8, true><<<GB, 256, 0, stream>>>(bufA, W4, b4, bufB, N);

    // --- FC head ---
    gemm_kernel<128, 32, 2, true><<<GB, 256, 0, stream>>>(bufB, Wf1, bf1, bufA, N);
    fc2_tanh_kernel<<<NB, 256, 0, stream>>>(bufA, Wf2, bf2, (float*)d_out, N);
}

// Round 4
// 575.231 us; speedup vs baseline: 1.7933x; 1.7933x over previous
//
#include <hip/hip_runtime.h>
#include <hip/hip_bf16.h>
#include <cmath>

// ---------------------------------------------------------------------------
// GCN: out = tanh(relu(relu(relu(relu(P(P(P(P(xW1+..)..) .. ))Wf1+bf1)Wf2+bf2
// P = D^-1/2 (A+I) D^-1/2 via CSR (dst-sorted) gather-sum, no float atomics.
// Associativity: aggregate at the *narrower* width of each layer.
// edge_index arrives as int32 (harness converts int64 inputs).
// R3: gemm<64,128,RT=8> spilled (VGPR=256, 895MB scratch traffic, 306us).
// R4: M-split blocks (64x64 tile, RT=4, 16 acc VGPRs), #pragma unroll 4.
// ---------------------------------------------------------------------------

__global__ void zero_kernel(int* p, int n) {
    int i = blockIdx.x * 256 + threadIdx.x;
    if (i < n) p[i] = 0;
}

__global__ void deg_kernel(const int* __restrict__ dst, int* __restrict__ cnt, int E) {
    int e = blockIdx.x * 256 + threadIdx.x;
    if (e < E) atomicAdd(&cnt[dst[e]], 1);
}

__global__ void dinv_kernel(const int* __restrict__ cnt, float* __restrict__ dinv, int N) {
    int i = blockIdx.x * 256 + threadIdx.x;
    if (i < N) dinv[i] = rsqrtf((float)cnt[i] + 1.0f);
}

// --- 3-kernel exclusive scan over per-node counts (N <= 512*256) -----------
__global__ void scan1_kernel(const int* __restrict__ cnt, int* __restrict__ row_ptr,
                             int* __restrict__ blk, int N) {
    __shared__ int s[256];
    int t = threadIdx.x;
    int idx = blockIdx.x * 256 + t;
    int v = (idx < N) ? cnt[idx] : 0;
    s[t] = v; __syncthreads();
    for (int off = 1; off < 256; off <<= 1) {
        int x = (t >= off) ? s[t - off] : 0;
        __syncthreads();
        s[t] += x;
        __syncthreads();
    }
    if (idx < N) row_ptr[idx] = s[t] - v;
    if (t == 255) blk[blockIdx.x] = s[255];
}

__global__ void scan2_kernel(int* __restrict__ blk, int NB) {
    __shared__ int s[512];
    int t = threadIdx.x;
    int v = (t < NB) ? blk[t] : 0;
    s[t] = v; __syncthreads();
    for (int off = 1; off < 512; off <<= 1) {
        int x = (t >= off) ? s[t - off] : 0;
        __syncthreads();
        s[t] += x;
        __syncthreads();
    }
    if (t < NB) blk[t] = s[t] - v;
}

__global__ void scan3_kernel(int* __restrict__ row_ptr, const int* __restrict__ blk,
                             int* __restrict__ cursor, int N, int E) {
    int idx = blockIdx.x * 256 + threadIdx.x;
    if (idx < N) {
        int v = row_ptr[idx] + blk[blockIdx.x];
        row_ptr[idx] = v;
        cursor[idx] = v;
    }
    if (idx == 0) row_ptr[N] = E;
}

__global__ void fill_kernel(const int* __restrict__ src, const int* __restrict__ dst,
                            const float* __restrict__ dinv, int* __restrict__ cursor,
                            int* __restrict__ csr_src, float* __restrict__ csr_w, int E) {
    int e = blockIdx.x * 256 + threadIdx.x;
    if (e >= E) return;
    int s = src[e];
    int d = dst[e];
    float w = dinv[s] * dinv[d];
    int pos = atomicAdd(&cursor[d], 1);
    csr_src[pos] = s;
    csr_w[pos] = w;
}

// --- aggregation: out[i,:] = sum_e w_e * z[src_e,:] + dinv[i]^2 * z[i,:] ----
template<int F, bool L1MODE>
__global__ __launch_bounds__(256) void agg_kernel(
        const float* __restrict__ z, const int* __restrict__ row_ptr,
        const int* __restrict__ csr_src, const float* __restrict__ csr_w,
        const float* __restrict__ dinv, const float* __restrict__ bias,
        float* __restrict__ out, int N) {
    constexpr int G = F / 4;       // lanes per row
    constexpr int S = 64 / G;      // edge slots per wave
    const int t = threadIdx.x;
    const int wave = t >> 6;
    const int lane = t & 63;
    const int slot = lane / G;
    const int f4 = lane % G;       // float4 index within row
    const int i = blockIdx.x * 4 + wave;
    if (i >= N) return;            // wave-uniform exit
    const int start = row_ptr[i];
    const int end = row_ptr[i + 1];
    float4 acc = {0.f, 0.f, 0.f, 0.f};
    for (int e = start + slot; e < end; e += S) {
        int s = csr_src[e];
        float w = csr_w[e];
        float4 zv = *(const float4*)&z[(size_t)s * F + f4 * 4];
        acc.x += w * zv.x; acc.y += w * zv.y; acc.z += w * zv.z; acc.w += w * zv.w;
    }
#pragma unroll
    for (int off = G; off < 64; off <<= 1) {
        acc.x += __shfl_xor(acc.x, off);
        acc.y += __shfl_xor(acc.y, off);
        acc.z += __shfl_xor(acc.z, off);
        acc.w += __shfl_xor(acc.w, off);
    }
    if (slot == 0) {
        float di = dinv[i];
        float d2 = di * di;
        float4 zs = *(const float4*)&z[(size_t)i * F + f4 * 4];
        float4 r;
        r.x = acc.x + d2 * zs.x; r.y = acc.y + d2 * zs.y;
        r.z = acc.z + d2 * zs.z; r.w = acc.w + d2 * zs.w;
        if (L1MODE) {
            float4 bv = *(const float4*)&bias[f4 * 4];
            r.x = fmaxf(r.x + bv.x, 0.f); r.y = fmaxf(r.y + bv.y, 0.f);
            r.z = fmaxf(r.z + bv.z, 0.f); r.w = fmaxf(r.w + bv.w, 0.f);
        }
        *(float4*)&out[(size_t)i * F + f4 * 4] = r;
    }
}

// --- register-tiled GEMM: 64-row x MB-col tile per 256-thread block ---------
// grid.x = ceil(N/64) * (M/MB). thread: RT rows x 4 cols => RT float4 accs.
template<int K, int M, int MB, int RT, bool BIAS_RELU>
__global__ __launch_bounds__(256) void gemm_kernel(
        const float* __restrict__ A, const float* __restrict__ W,
        const float* __restrict__ bias, float* __restrict__ out, int N) {
    constexpr int CG = MB / 4;
    constexpr int TM = (256 / CG) * RT;
    constexpr int KP = K + 4;            // 2-way bank alias on As reads (free)
    constexpr int MSPLIT = M / MB;
    static_assert(TM == 64, "tile rows");
    __shared__ float As[TM * KP];
    __shared__ float Ws[K * MB];
    __shared__ float bs[MB];
    const int t = threadIdx.x;
    const int base = (blockIdx.x / MSPLIT) * TM;
    const int colb = (blockIdx.x % MSPLIT) * MB;
    const int rows_valid = min(TM, N - base);
    constexpr int KD4 = K / 4;
    for (int idx = t; idx < TM * KD4; idx += 256) {
        int row = idx / KD4, kc = idx % KD4;
        if (row < rows_valid)
            *(float4*)&As[row * KP + kc * 4] = *(const float4*)&A[(size_t)(base + row) * K + kc * 4];
    }
    constexpr int MD4 = MB / 4;
    for (int idx = t; idx < K * MD4; idx += 256) {
        int k = idx / MD4, c4 = idx % MD4;
        *(float4*)&Ws[k * MB + c4 * 4] = *(const float4*)&W[(size_t)k * M + colb + c4 * 4];
    }
    if (BIAS_RELU && t < MB) bs[t] = bias[colb + t];
    __syncthreads();

    const int tc = t % CG;
    const int r0 = (t / CG) * RT;
    const int c0 = tc * 4;
    float4 acc[RT];
#pragma unroll
    for (int r = 0; r < RT; r++) acc[r] = {0.f, 0.f, 0.f, 0.f};

#pragma unroll 4
    for (int k = 0; k < K; k += 4) {
        float4 w0 = *(const float4*)&Ws[(k + 0) * MB + c0];
        float4 w1 = *(const float4*)&Ws[(k + 1) * MB + c0];
        float4 w2 = *(const float4*)&Ws[(k + 2) * MB + c0];
        float4 w3 = *(const float4*)&Ws[(k + 3) * MB + c0];
#pragma unroll
        for (int r = 0; r < RT; r++) {
            float4 av = *(const float4*)&As[(r0 + r) * KP + k];
            acc[r].x += av.x * w0.x + av.y * w1.x + av.z * w2.x + av.w * w3.x;
            acc[r].y += av.x * w0.y + av.y * w1.y + av.z * w2.y + av.w * w3.y;
            acc[r].z += av.x * w0.z + av.y * w1.z + av.z * w2.z + av.w * w3.z;
            acc[r].w += av.x * w0.w + av.y * w1.w + av.z * w2.w + av.w * w3.w;
        }
    }
#pragma unroll
    for (int r = 0; r < RT; r++) {
        int row = base + r0 + r;
        if (row < N) {
            float4 v = acc[r];
            if (BIAS_RELU) {
                float4 bv = *(const float4*)&bs[c0];
                v.x = fmaxf(v.x + bv.x, 0.f); v.y = fmaxf(v.y + bv.y, 0.f);
                v.z = fmaxf(v.z + bv.z, 0.f); v.w = fmaxf(v.w + bv.w, 0.f);
            }
            *(float4*)&out[(size_t)row * M + colb + c0] = v;
        }
    }
}

// --- final FC: K=32, M=10, tanh --------------------------------------------
__global__ __launch_bounds__(256) void fc2_tanh_kernel(
        const float* __restrict__ A, const float* __restrict__ W,
        const float* __restrict__ bias, float* __restrict__ out, int N) {
    __shared__ float wt[10][36];
    __shared__ float bs[10];
    int t = threadIdx.x;
    for (int idx = t; idx < 320; idx += 256) { int k = idx / 10, m = idx % 10; wt[m][k] = W[idx]; }
    if (t < 10) bs[t] = bias[t];
    __syncthreads();
    int row = blockIdx.x * 256 + t;
    if (row >= N) return;
    float a[32];
    const float4* ap = (const float4*)(A + (size_t)row * 32);
#pragma unroll
    for (int j = 0; j < 8; j++) {
        float4 v = ap[j];
        a[4 * j] = v.x; a[4 * j + 1] = v.y; a[4 * j + 2] = v.z; a[4 * j + 3] = v.w;
    }
#pragma unroll
    for (int m = 0; m < 10; m++) {
        float acc = bs[m];
#pragma unroll
        for (int k = 0; k < 32; k++) acc += a[k] * wt[m][k];
        out[(size_t)row * 10 + m] = tanhf(acc);
    }
}

extern "C" void kernel_launch(void* const* d_in, const int* in_sizes, int n_in,
                              void* d_out, int out_size, void* d_ws, size_t ws_size,
                              hipStream_t stream) {
    const float* x   = (const float*)d_in[0];
    const int*   ei  = (const int*)d_in[1];     // int32 on device
    const float* W1  = (const float*)d_in[2];
    const float* b1  = (const float*)d_in[3];
    const float* W2  = (const float*)d_in[4];
    const float* b2  = (const float*)d_in[5];
    const float* W3  = (const float*)d_in[6];
    const float* b3  = (const float*)d_in[7];
    const float* W4  = (const float*)d_in[8];
    const float* b4  = (const float*)d_in[9];
    const float* Wf1 = (const float*)d_in[10];
    const float* bf1 = (const float*)d_in[11];
    const float* Wf2 = (const float*)d_in[12];
    const float* bf2 = (const float*)d_in[13];

    const int N = in_sizes[0] / 128;   // 100000
    const int E = in_sizes[1] / 2;     // 1600000
    const int* e_src = ei;
    const int* e_dst = ei + E;

    char* p = (char*)d_ws;
    auto carve = [&](size_t bytes) -> void* {
        void* r = (void*)p;
        p += (bytes + 255) & ~(size_t)255;
        return r;
    };
    int*   cnt     = (int*)carve((size_t)N * 4);          // reused as cursor
    float* dinv    = (float*)carve((size_t)N * 4);
    int*   row_ptr = (int*)carve((size_t)(N + 1) * 4);
    int*   blk     = (int*)carve(512 * 4);
    int*   csr_src = (int*)carve((size_t)E * 4);
    float* csr_w   = (float*)carve((size_t)E * 4);
    float* bufA    = (float*)carve((size_t)N * 64 * 4);
    float* bufB    = (float*)carve((size_t)N * 128 * 4);

    const int NB  = (N + 255) / 256;   // 391
    const int EB  = (E + 255) / 256;
    const int AGB = (N + 3) / 4;
    const int GB  = (N + 63) / 64;     // 1563 row-blocks

    // --- graph preprocessing: degree, dinv, CSR ---
    zero_kernel<<<NB, 256, 0, stream>>>(cnt, N);
    deg_kernel<<<EB, 256, 0, stream>>>(e_dst, cnt, E);
    dinv_kernel<<<NB, 256, 0, stream>>>(cnt, dinv, N);
    scan1_kernel<<<NB, 256, 0, stream>>>(cnt, row_ptr, blk, N);
    scan2_kernel<<<1, 512, 0, stream>>>(blk, NB);
    scan3_kernel<<<NB, 256, 0, stream>>>(row_ptr, blk, cnt, N, E);
    fill_kernel<<<EB, 256, 0, stream>>>(e_src, e_dst, dinv, cnt, csr_src, csr_w, E);

    // --- L1 (128->16): GEMM first (narrow side), then aggregate+bias+relu ---
    gemm_kernel<128, 16, 16, 1, false><<<GB, 256, 0, stream>>>(x, W1, nullptr, bufA, N);
    agg_kernel<16, true><<<AGB, 256, 0, stream>>>(bufA, row_ptr, csr_src, csr_w, dinv, b1, bufB, N);

    // --- L2 (16->32): aggregate first, then GEMM+bias+relu ---
    agg_kernel<16, false><<<AGB, 256, 0, stream>>>(bufB, row_ptr, csr_src, csr_w, dinv, nullptr, bufA, N);
    gemm_kernel<16, 32, 32, 2, true><<<GB, 256, 0, stream>>>(bufA, W2, b2, bufB, N);

    // --- L3 (32->64) ---
    agg_kernel<32, false><<<AGB, 256, 0, stream>>>(bufB, row_ptr, csr_src, csr_w, dinv, nullptr, bufA, N);
    gemm_kernel<32, 64, 64, 4, true><<<GB, 256, 0, stream>>>(bufA, W3, b3, bufB, N);

    // --- L4 (64->128): aggregate at width 64, then M-split GEMM ---
    agg_kernel<64, false><<<AGB, 256, 0, stream>>>(bufB, row_ptr, csr_src, csr_w, dinv, nullptr, bufA, N);
    gemm_kernel<64, 128, 64, 4, true><<<GB * 2, 256, 0, stream>>>(bufA, W4, b4, bufB, N);

    // --- FC head ---
    gemm_kernel<128, 32, 32, 2, true><<<GB, 256, 0, stream>>>(bufB, Wf1, bf1, bufA, N);
    fc2_tanh_kernel<<<NB, 256, 0, stream>>>(bufA, Wf2, bf2, (float*)d_out, N);
}